// Round 7
// baseline (45885.059 us; speedup 1.0000x reference)
//
#include <hip/hip_runtime.h>
#include <cstdint>
#include <cstddef>

// Problem constants (LSTM_66726611911224)
#define TT   2048
#define BB   64
#define IND  128
#define HH   256
#define GG   1024   // 4*H, gate order i,f,g,o
#define OUTD 128
#define TC   64     // time-chunk size
#define NCH  (TT / TC)   // 32

// ---- workspace layout (bytes) ----
static const size_t XG0_OFF    = 0;                         // f16 [TC*B][1024] = 8,388,608
static const size_t XG1_OFF    = 8388608ull;                // f16 [TC*B][1024] = 8,388,608
static const size_t HST0_OFF   = 16777216ull;               // f16 [TC*B][256]  = 2,097,152
static const size_t HST1_OFF   = 18874368ull;               // f16 [TC*B][256]  = 2,097,152
static const size_t WHH_OFF    = 20971520ull;               // uint4 [4][16][512] = 524,288
static const size_t WIH_OFF    = WHH_OFF  + 524288ull;      // uint4 [16384]    =    262,144
static const size_t WOUT_OFF   = WIH_OFF  + 262144ull;      // f16 [128][256]   =     65,536
static const size_t BSUM_OFF   = WOUT_OFF + 65536ull;       // f32 [1024]       =      4,096
static const size_t HSTATE_OFF = BSUM_OFF + 4096ull;        // f16 [64][256]    =     32,768
static const size_t CSTATE_OFF = HSTATE_OFF + 32768ull;     // f32 [64][256]    =     65,536
static const size_t FLAG_OFF   = CSTATE_OFF + 65536ull;     // int [128] sync flags (+pad)
static const size_t WS_NEEDED  = FLAG_OFF + 4096ull;        // = 21,929,984

// fused-kernel dynamic LDS: consumer o/g weights 128 KB + h ping-pong 1 KB
static const int SMEM_SZ = 131072 + 1024;                   // 132,096 B (<160 KB/CU)

typedef _Float16 h2 __attribute__((ext_vector_type(2)));

union U16 { uint4 u; h2 h[4]; };          // 16B <-> 4x half2
union HU  { unsigned short u; _Float16 h; };

__device__ __forceinline__ float fdot2f(h2 a, h2 b, float c) {
#if __has_builtin(__builtin_amdgcn_fdot2)
  return __builtin_amdgcn_fdot2(a, b, c, false);   // v_dot2_f32_f16, f32 accumulate
#else
  return c + (float)a.x * (float)b.x + (float)a.y * (float)b.y;
#endif
}

__device__ __forceinline__ float sigm(float x) { return 1.f / (1.f + __expf(-x)); }
__device__ __forceinline__ float tanh_fast(float x) {
  float ax = fabsf(x);
  float e  = __expf(-2.f * ax);          // in (0,1], no overflow
  float r  = (1.f - e) / (1.f + e);
  return x < 0.f ? -r : r;
}

// ---------------- K0: pack weights to f16 layouts, bias sum, zero flags ----------------
// W_hh layout: uint4 index = rr*8192 + q*512 + u2, u2 = u*2+half
//   rr 0/1/2/3 -> rows u / 256+u / 768+u / 512+u  (i, f, o, g)
//   k-range of the uint4: half*128 + q*8 .. +8
__global__ void k0_pack(const float* __restrict__ Whh, const float* __restrict__ Wih,
                        const float* __restrict__ Wout, const float* __restrict__ bih,
                        const float* __restrict__ bhh, uint8_t* __restrict__ ws) {
  int tid = blockIdx.x * 256 + threadIdx.x;
  if (tid < 32768) {
    int rr = tid >> 13, rem = tid & 8191;
    int q = rem >> 9, u2 = rem & 511;
    int u = u2 >> 1, hf = u2 & 1;
    int row = (rr == 0) ? u : (rr == 1) ? 256 + u : (rr == 2) ? 768 + u : 512 + u;
    int kb = hf * 128 + q * 8;
    const float4* s = (const float4*)(Whh + (size_t)row * HH + kb);
    float4 v0 = s[0], v1 = s[1];
    U16 o;
    o.h[0].x = (_Float16)v0.x; o.h[0].y = (_Float16)v0.y;
    o.h[1].x = (_Float16)v0.z; o.h[1].y = (_Float16)v0.w;
    o.h[2].x = (_Float16)v1.x; o.h[2].y = (_Float16)v1.y;
    o.h[3].x = (_Float16)v1.z; o.h[3].y = (_Float16)v1.w;
    ((uint4*)(ws + WHH_OFF))[tid] = o.u;
  } else if (tid < 65536) {                // W_out -> f16, row-major [128][256]
    int t2 = tid - 32768;
    ((_Float16*)(ws + WOUT_OFF))[t2] = (_Float16)Wout[t2];
  } else if (tid < 81920) {                // W_ih -> f16, row-major [1024][128], 8-packed
    int i = tid - 65536;
    const float4* s = (const float4*)(Wih + (size_t)i * 8);
    float4 v0 = s[0], v1 = s[1];
    U16 o;
    o.h[0].x = (_Float16)v0.x; o.h[0].y = (_Float16)v0.y;
    o.h[1].x = (_Float16)v0.z; o.h[1].y = (_Float16)v0.w;
    o.h[2].x = (_Float16)v1.x; o.h[2].y = (_Float16)v1.y;
    o.h[3].x = (_Float16)v1.z; o.h[3].y = (_Float16)v1.w;
    ((uint4*)(ws + WIH_OFF))[i] = o.u;
  } else if (tid < 82944) {                // bias sum
    int n = tid - 81920;
    ((float*)(ws + BSUM_OFF))[n] = bih[n] + bhh[n];
  } else if (tid < 83072) {                // zero pair-sync flags (once per launch)
    ((int*)(ws + FLAG_OFF))[tid - 82944] = 0;
  }
}

// ---------------- K1: xg for chunk 0 only (later chunks made by producer wgs) ----
__global__ void __launch_bounds__(256) k1_xgemm(const float* __restrict__ x,
                                                uint8_t* __restrict__ ws) {
  const uint4* Wp   = (const uint4*)(ws + WIH_OFF);
  const float* bsum = (const float*)(ws + BSUM_OFF);
  _Float16*    xg   = (_Float16*)(ws + XG0_OFF);

  const int s = blockIdx.x >> 4;                       // col segment (64 cols), 16 segs
  const int m = ((blockIdx.x & 15) << 8) + threadIdx.x; // row 0..4095

  __shared__ uint4 wlds[1024];                         // 64 rows x 16 uint4
  __shared__ float bsl[64];
  #pragma unroll
  for (int i = 0; i < 4; ++i)
    wlds[i * 256 + threadIdx.x] = Wp[(size_t)(s << 6) * 16 + i * 256 + threadIdx.x];
  if (threadIdx.x < 64) bsl[threadIdx.x] = bsum[(s << 6) + threadIdx.x];
  __syncthreads();

  const float4* xr = (const float4*)(x + (size_t)m * IND);   // t0 = 0
  h2 xv[64];
  #pragma unroll
  for (int i = 0; i < 32; ++i) {
    float4 v = xr[i];
    xv[2*i  ].x = (_Float16)v.x; xv[2*i  ].y = (_Float16)v.y;
    xv[2*i+1].x = (_Float16)v.z; xv[2*i+1].y = (_Float16)v.w;
  }
  _Float16* xgrow = xg + (size_t)m * GG + (s << 6);
  for (int g = 0; g < 8; ++g) {
    float acc[8];
    #pragma unroll
    for (int j = 0; j < 8; ++j) {
      const uint4* wr = &wlds[(g * 8 + j) * 16];
      float a = bsl[g * 8 + j];
      #pragma unroll
      for (int q = 0; q < 16; ++q) {
        U16 w; w.u = wr[q];
        a = fdot2f(w.h[0], xv[4*q+0], a);
        a = fdot2f(w.h[1], xv[4*q+1], a);
        a = fdot2f(w.h[2], xv[4*q+2], a);
        a = fdot2f(w.h[3], xv[4*q+3], a);
      }
      acc[j] = a;
    }
    U16 o;
    #pragma unroll
    for (int p = 0; p < 4; ++p) { o.h[p].x = (_Float16)acc[2*p]; o.h[p].y = (_Float16)acc[2*p+1]; }
    *(uint4*)(xgrow + g * 8) = o.u;
  }
}

// ---------------- Fused per-chunk kernel: 3 wg roles ----------------
// grid 224 x 512 threads:
//   wg 0..127   consumer : recurrence for chunk ch, 2 wgs per batch element
//                          (wg j = units 0..127 of batch j&63, wg j+64 = units 128..255)
//   wg 128..191 producer : xg GEMM for chunk ch+1 (ping-pong buffer)
//   wg 192..223 y        : output projection of chunk ch-1 from hst ping-pong
//
// ROUND-7 RESTRUCTURE (rounds 0/1/4/5/6 counter evidence): the per-wave
// unified register cap is 128 on this compiler (512thr) — a single CU can
// never hold its 512 KB weight slice, so 1-CU-per-batch designs re-stream
// ~384 KB/step from L2 (~3000 cy = the 4416 cy/step wall; FETCH/scratch
// A/Bs in r5/r6 confirmed). Fix: 2 CUs per batch element (unit-split).
// Per-CU weights 256 KB: i/f in 64 pinned regs (fits the 128 cap), o/g in
// 128 KB LDS -> VMEM weight stream is ZERO. Per step the halves exchange h
// (256 B each way) through the hst buffer (written anyway) with a
// device-scope flag handshake; pair (j, j+64) lands on the same XCD under
// round-robin so the exchange is L2-local (perf-only assumption).
// Co-residency: 224 wgs x 129 KB LDS = 1 wg/CU <= 256 CUs -> no deadlock.
__global__ void __launch_bounds__(512)
k2_fused(const float* __restrict__ x,
         uint8_t* __restrict__ ws,
         const float* __restrict__ b_out,
         float* __restrict__ out, int ch) {
  extern __shared__ __align__(16) uint8_t smem[];
  const int bi  = blockIdx.x;
  const int tid = threadIdx.x;

  if (bi < 128) {
    // ================= consumer (pairwise) =================
    if (ch >= NCH) return;
    const int b    = bi & 63;                         // batch element
    const int uh   = bi >> 6;                         // 0: units 0-127, 1: 128-255
    const int u_l  = tid >> 2;                        // local unit 0..127
    const int qk   = tid & 3;                         // k-quarter of FULL k=256
    const int u    = (uh << 7) + u_l;                 // global unit
    const int qoff = (qk & 1) << 3;                   // q-offset within k-half
    const int u2g  = (uh << 8) + (tid >> 1);          // WHH column (global)
    const int u2l  = tid >> 1;                        // LDS column (local 0..255)
    const int pb   = (uh ^ 1) << 7;                   // partner unit base
    const int t0   = ch * TC;

    const uint4* WR = (const uint4*)(ws + WHH_OFF);   // [rr][q][u2]
    const unsigned short* xp = (const unsigned short*)(ws + ((ch & 1) ? XG1_OFF : XG0_OFF));
    unsigned short* hstx = (unsigned short*)(ws + ((ch & 1) ? HST1_OFF : HST0_OFF));
    _Float16* hstate = (_Float16*)(ws + HSTATE_OFF);
    float*    cstate = (float*)(ws + CSTATE_OFF);
    int*      flags  = (int*)(ws + FLAG_OFF);

    uint4*          gws   = (uint4*)smem;             // o:[16][256] then g:[16][256] = 128 KB
    unsigned short* h_lds = (unsigned short*)(smem + 131072); // [2][256] ping-pong

    // one-time: i/f quarter-rows into registers (64 h2), pinned resident
    h2 wi[32], wf[32];
    #pragma unroll
    for (int j = 0; j < 8; ++j) {
      U16 a;
      a.u = WR[(qoff + j) * 512 + u2g];
      wi[4*j+0]=a.h[0]; wi[4*j+1]=a.h[1]; wi[4*j+2]=a.h[2]; wi[4*j+3]=a.h[3];
      a.u = WR[8192 + (qoff + j) * 512 + u2g];
      wf[4*j+0]=a.h[0]; wf[4*j+1]=a.h[1]; wf[4*j+2]=a.h[2]; wf[4*j+3]=a.h[3];
    }
    #pragma unroll
    for (int k = 0; k < 32; ++k) {
      asm volatile("" : "+v"(wi[k]));
      asm volatile("" : "+v"(wf[k]));
    }
    // one-time: stage o (rr=2) and g (rr=3) half-columns into LDS
    #pragma unroll
    for (int j = 0; j < 8; ++j) {
      int t2 = j * 512 + tid;
      int qq = t2 >> 8, idx = t2 & 255;
      gws[qq * 256 + idx]        = WR[16384 + qq * 512 + (uh << 8) + idx];  // o
      gws[4096 + qq * 256 + idx] = WR[24576 + qq * 512 + (uh << 8) + idx];  // g
    }

    if (tid < 32) {                                   // full h_{-1} -> buf0
      uint4 z = make_uint4(0u, 0u, 0u, 0u);
      ((uint4*)h_lds)[tid] = (t0 == 0) ? z : ((const uint4*)(hstate + (size_t)b * HH))[tid];
    }
    float c = 0.f;
    if (t0 != 0) c = cstate[(size_t)b * HH + u];      // all 4 quad lanes same c

    const size_t xrow = (size_t)b * GG;
    __syncthreads();

    for (int tt = 0; tt < TC; ++tt) {
      // this step's xg at loop top: latency hides under the dot phase
      const size_t nx = xrow + (size_t)tt * (BB * GG);
      HU xi, xf, xgv, xo;
      xi.u  = xp[nx + u];
      xf.u  = xp[nx + 256 + u];
      xgv.u = xp[nx + 512 + u];
      xo.u  = xp[nx + 768 + u];

      float ai = 0.f, af = 0.f, ag = 0.f, ao = 0.f;
      const uint4* hv = ((const uint4*)h_lds) + (tt & 1) * 32 + qk * 8;
      #pragma unroll
      for (int j = 0; j < 8; ++j) {
        U16 hh; hh.u = hv[j];
        U16 ow; ow.u = gws[(qoff + j) * 256 + u2l];
        U16 gw; gw.u = gws[4096 + (qoff + j) * 256 + u2l];
        #pragma unroll
        for (int jj = 0; jj < 4; ++jj) {
          ai = fdot2f(wi[4*j+jj], hh.h[jj], ai);
          af = fdot2f(wf[4*j+jj], hh.h[jj], af);
          ag = fdot2f(gw.h[jj],   hh.h[jj], ag);
          ao = fdot2f(ow.h[jj],   hh.h[jj], ao);
        }
      }
      // quad reduce over k-quarters (proven numerics from r4, absmax pass)
      ai += __shfl_xor(ai, 1); ai += __shfl_xor(ai, 2);
      af += __shfl_xor(af, 1); af += __shfl_xor(af, 2);
      ag += __shfl_xor(ag, 1); ag += __shfl_xor(ag, 2);
      ao += __shfl_xor(ao, 1); ao += __shfl_xor(ao, 2);
      float gi = sigm(ai + (float)xi.h);
      float gf = sigm(af + (float)xf.h);
      float gg = tanh_fast(ag + (float)xgv.h);
      float go = sigm(ao + (float)xo.h);
      c = gf * c + gi * gg;
      float hn = go * tanh_fast(c);

      const int np = (tt + 1) & 1;
      if (qk == 0) {                                  // own-half stores
        HU hvs; hvs.h = (_Float16)hn;
        h_lds[np * HH + u] = hvs.u;
        hstx[((size_t)tt * BB + b) * HH + u] = hvs.u; // also the exchange buffer
        if (t0 + tt == TT - 1) {
          const size_t tail = (size_t)TT * BB * OUTD;
          out[tail + (size_t)b * HH + u] = hn;                       // h_T
          out[tail + (size_t)BB * HH + (size_t)b * HH + u] = c;      // c_T
        }
      }
      __threadfence();                                // writers' stores device-visible
      __syncthreads();                                // all fences done; own h_lds half set
      const int gstep = t0 + tt + 1;
      if (tid == 0)
        __hip_atomic_store(&flags[bi], gstep, __ATOMIC_RELEASE, __HIP_MEMORY_SCOPE_AGENT);
      if (tid < 128) {
        while (__hip_atomic_load(&flags[bi ^ 64], __ATOMIC_ACQUIRE, __HIP_MEMORY_SCOPE_AGENT) < gstep) {}
        h_lds[np * HH + pb + tid] = hstx[((size_t)tt * BB + b) * HH + pb + tid];
      }
      __syncthreads();                                // full h(t+1) in h_lds
    }

    // persist state (TC even -> final h is in buf0); each wg its own half
    if (tid < 16) ((uint4*)(hstate + (size_t)b * HH))[(uh << 4) + tid] =
                  ((const uint4*)h_lds)[(uh << 4) + tid];
    if (qk == 0) cstate[(size_t)b * HH + u] = c;

  } else if (bi < 192) {
    // ================= producer: xg for chunk ch+1 (64 wgs, 2 rows/thread) ======
    if (ch + 1 >= NCH) return;
    const int p    = bi - 128;
    const int seg  = p >> 2;                          // 0..15 (64-col segment)
    const int rowg = p & 3;
    const int t0n  = (ch + 1) * TC;

    const uint4* Wp   = (const uint4*)(ws + WIH_OFF);
    const float* bsum = (const float*)(ws + BSUM_OFF);
    _Float16*    xgn  = (_Float16*)(ws + (((ch + 1) & 1) ? XG1_OFF : XG0_OFF));

    uint4* wlds = (uint4*)smem;                       // 1024 uint4 = 16 KB
    float* bsl  = (float*)(smem + 16384);
    wlds[tid]       = Wp[(size_t)(seg << 6) * 16 + tid];
    wlds[tid + 512] = Wp[(size_t)(seg << 6) * 16 + 512 + tid];
    if (tid < 64) bsl[tid] = bsum[(seg << 6) + tid];
    __syncthreads();

    for (int rr = 0; rr < 2; ++rr) {
      const int m = rowg * 1024 + rr * 512 + tid;     // 0..4095
      const float4* xr = (const float4*)(x + ((size_t)t0n * BB + m) * IND);
      h2 xv[64];
      #pragma unroll
      for (int i = 0; i < 32; ++i) {
        float4 v = xr[i];
        xv[2*i  ].x = (_Float16)v.x; xv[2*i  ].y = (_Float16)v.y;
        xv[2*i+1].x = (_Float16)v.z; xv[2*i+1].y = (_Float16)v.w;
      }
      _Float16* xgrow = xgn + (size_t)m * GG + (seg << 6);
      for (int g = 0; g < 8; ++g) {
        float acc[8];
        #pragma unroll
        for (int j = 0; j < 8; ++j) {
          const uint4* wr = &wlds[(g * 8 + j) * 16];
          float a = bsl[g * 8 + j];
          #pragma unroll
          for (int q = 0; q < 16; ++q) {
            U16 w; w.u = wr[q];
            a = fdot2f(w.h[0], xv[4*q+0], a);
            a = fdot2f(w.h[1], xv[4*q+1], a);
            a = fdot2f(w.h[2], xv[4*q+2], a);
            a = fdot2f(w.h[3], xv[4*q+3], a);
          }
          acc[j] = a;
        }
        U16 o;
        #pragma unroll
        for (int pk = 0; pk < 4; ++pk) { o.h[pk].x = (_Float16)acc[2*pk]; o.h[pk].y = (_Float16)acc[2*pk+1]; }
        *(uint4*)(xgrow + g * 8) = o.u;
      }
    }

  } else {
    // ================= y: output projection for chunk ch-1 =================
    if (ch < 1) return;
    const int yb   = bi - 192;                        // 0..31
    const int seg  = yb & 15;                         // 8-col segment
    const int rowg = yb >> 4;                         // 0..1
    const int t0p  = (ch - 1) * TC;

    const _Float16* hstp = (const _Float16*)(ws + (((ch - 1) & 1) ? HST1_OFF : HST0_OFF));
    const uint4* WO = (const uint4*)(ws + WOUT_OFF);  // [128][32] uint4

    uint4* wlds = (uint4*)smem;                       // 256 uint4 = 4 KB
    float* bsl  = (float*)(smem + 4096);
    if (tid < 256) wlds[tid] = WO[(size_t)(seg * 8) * 32 + tid];
    if (tid < 8)   bsl[tid]  = b_out[seg * 8 + tid];
    __syncthreads();

    #pragma unroll
    for (int rr = 0; rr < 4; ++rr) {                  // 4 rows per thread
      const int r = rowg * 2048 + rr * 512 + tid;     // 0..4095
      const uint4* hr = (const uint4*)(hstp + (size_t)r * HH);
      float acc[8];
      #pragma unroll
      for (int j = 0; j < 8; ++j) acc[j] = bsl[j];
      #pragma unroll 4
      for (int q = 0; q < 32; ++q) {
        U16 hh; hh.u = hr[q];
        #pragma unroll
        for (int j = 0; j < 8; ++j) {
          U16 w; w.u = wlds[j * 32 + q];
          acc[j] = fdot2f(w.h[0], hh.h[0], acc[j]);
          acc[j] = fdot2f(w.h[1], hh.h[1], acc[j]);
          acc[j] = fdot2f(w.h[2], hh.h[2], acc[j]);
          acc[j] = fdot2f(w.h[3], hh.h[3], acc[j]);
        }
      }
      float* orow = out + ((size_t)t0p * BB + r) * OUTD + seg * 8;
      *(float4*)(orow)     = make_float4(acc[0], acc[1], acc[2], acc[3]);
      *(float4*)(orow + 4) = make_float4(acc[4], acc[5], acc[6], acc[7]);
    }
  }
}

extern "C" void kernel_launch(void* const* d_in, const int* in_sizes, int n_in,
                              void* d_out, int out_size, void* d_ws, size_t ws_size,
                              hipStream_t stream) {
  const float* input = (const float*)d_in[0];
  const float* W_ih  = (const float*)d_in[1];
  const float* W_hh  = (const float*)d_in[2];
  const float* b_ih  = (const float*)d_in[3];
  const float* b_hh  = (const float*)d_in[4];
  const float* W_out = (const float*)d_in[5];
  const float* b_out = (const float*)d_in[6];
  float*   out = (float*)d_out;
  uint8_t* ws  = (uint8_t*)d_ws;

  if (ws_size < WS_NEEDED) return;   // fail validation cleanly instead of faulting

  // allow 129 KB dynamic LDS (gfx950: 160 KB/CU); host-side + idempotent ->
  // safe under graph capture (proven in prior rounds).
  hipFuncSetAttribute((const void*)k2_fused,
                      hipFuncAttributeMaxDynamicSharedMemorySize, SMEM_SZ);

  hipLaunchKernelGGL(k0_pack,  dim3(325), dim3(256), 0, stream,
                     W_hh, W_ih, W_out, b_ih, b_hh, ws);
  hipLaunchKernelGGL(k1_xgemm, dim3(256), dim3(256), 0, stream, input, ws); // chunk 0 xg
  for (int ch = 0; ch <= NCH; ++ch) {   // ch==NCH: only y-role (last chunk's output)
    hipLaunchKernelGGL(k2_fused, dim3(224), dim3(512), SMEM_SZ, stream,
                       input, ws, b_out, out, ch);
  }
}

// Round 8
// 4073.548 us; speedup vs baseline: 11.2642x; 11.2642x over previous
//
#include <hip/hip_runtime.h>
#include <cstdint>
#include <cstddef>

// Problem constants (LSTM_66726611911224)
#define TT   2048
#define BB   64
#define IND  128
#define HH   256
#define GG   1024   // 4*H, gate order i,f,g,o
#define OUTD 128
#define TC   64     // time-chunk size
#define NCH  (TT / TC)   // 32

// ---- workspace layout (bytes), total = 21,925,888 (proven available) ----
static const size_t XG0_OFF    = 0;                         // f16 [TC*B][1024] = 8,388,608
static const size_t XG1_OFF    = 8388608ull;                // f16 [TC*B][1024] = 8,388,608
static const size_t HST0_OFF   = 16777216ull;               // f16 [TC*B][256]  = 2,097,152
static const size_t HST1_OFF   = 18874368ull;               // f16 [TC*B][256]  = 2,097,152
static const size_t WHH_OFF    = 20971520ull;               // uint4 [4][16][512] = 524,288
static const size_t WIH_OFF    = WHH_OFF  + 524288ull;      // uint4 [16384]    =    262,144
static const size_t WOUT_OFF   = WIH_OFF  + 262144ull;      // f16 [128][256]   =     65,536
static const size_t BSUM_OFF   = WOUT_OFF + 65536ull;       // f32 [1024]       =      4,096
static const size_t HSTATE_OFF = BSUM_OFF + 4096ull;        // f16 [64][256]    =     32,768
static const size_t CSTATE_OFF = HSTATE_OFF + 32768ull;     // f32 [64][256]    =     65,536
static const size_t WS_NEEDED  = CSTATE_OFF + 65536ull;     // = 21,925,888

// fused-kernel dynamic LDS: consumer g-weights 128 KB + h ping-pong 1 KB
static const int SMEM_SZ = 131072 + 1024;                   // 132,096 B (<160 KB/CU)

typedef _Float16 h2 __attribute__((ext_vector_type(2)));

union U16 { uint4 u; h2 h[4]; };          // 16B <-> 4x half2
union HU  { unsigned short u; _Float16 h; };

__device__ __forceinline__ float fdot2f(h2 a, h2 b, float c) {
#if __has_builtin(__builtin_amdgcn_fdot2)
  return __builtin_amdgcn_fdot2(a, b, c, false);   // v_dot2_f32_f16, f32 accumulate
#else
  return c + (float)a.x * (float)b.x + (float)a.y * (float)b.y;
#endif
}

__device__ __forceinline__ float sigm(float x) { return 1.f / (1.f + __expf(-x)); }
__device__ __forceinline__ float tanh_fast(float x) {
  float ax = fabsf(x);
  float e  = __expf(-2.f * ax);          // in (0,1], no overflow
  float r  = (1.f - e) / (1.f + e);
  return x < 0.f ? -r : r;
}

// ---------------- K0: pack weights to f16 layouts, bias sum ----------------
// W_hh layout: uint4 index = rr*8192 + q*512 + u2, u2 = u*2+half
//   rr 0/1/2/3 -> rows u / 256+u / 768+u / 512+u  (i, f, o, g)
//   k-range of the uint4: half*128 + q*8 .. +8
// Consumer lane L has u2 == tid -> all weight/LDS accesses per-lane linear.
__global__ void k0_pack(const float* __restrict__ Whh, const float* __restrict__ Wih,
                        const float* __restrict__ Wout, const float* __restrict__ bih,
                        const float* __restrict__ bhh, uint8_t* __restrict__ ws) {
  int tid = blockIdx.x * 256 + threadIdx.x;
  if (tid < 32768) {
    int rr = tid >> 13, rem = tid & 8191;
    int q = rem >> 9, u2 = rem & 511;
    int u = u2 >> 1, hf = u2 & 1;
    int row = (rr == 0) ? u : (rr == 1) ? 256 + u : (rr == 2) ? 768 + u : 512 + u;
    int kb = hf * 128 + q * 8;
    const float4* s = (const float4*)(Whh + (size_t)row * HH + kb);
    float4 v0 = s[0], v1 = s[1];
    U16 o;
    o.h[0].x = (_Float16)v0.x; o.h[0].y = (_Float16)v0.y;
    o.h[1].x = (_Float16)v0.z; o.h[1].y = (_Float16)v0.w;
    o.h[2].x = (_Float16)v1.x; o.h[2].y = (_Float16)v1.y;
    o.h[3].x = (_Float16)v1.z; o.h[3].y = (_Float16)v1.w;
    ((uint4*)(ws + WHH_OFF))[tid] = o.u;
  } else if (tid < 65536) {                // W_out -> f16, row-major [128][256]
    int t2 = tid - 32768;
    ((_Float16*)(ws + WOUT_OFF))[t2] = (_Float16)Wout[t2];
  } else if (tid < 81920) {                // W_ih -> f16, row-major [1024][128], 8-packed
    int i = tid - 65536;
    const float4* s = (const float4*)(Wih + (size_t)i * 8);
    float4 v0 = s[0], v1 = s[1];
    U16 o;
    o.h[0].x = (_Float16)v0.x; o.h[0].y = (_Float16)v0.y;
    o.h[1].x = (_Float16)v0.z; o.h[1].y = (_Float16)v0.w;
    o.h[2].x = (_Float16)v1.x; o.h[2].y = (_Float16)v1.y;
    o.h[3].x = (_Float16)v1.z; o.h[3].y = (_Float16)v1.w;
    ((uint4*)(ws + WIH_OFF))[i] = o.u;
  } else if (tid < 82944) {                // bias sum
    int n = tid - 81920;
    ((float*)(ws + BSUM_OFF))[n] = bih[n] + bhh[n];
  }
}

// ---------------- K1: xg for chunk 0 only (later chunks made by producer wgs) ----
__global__ void __launch_bounds__(256) k1_xgemm(const float* __restrict__ x,
                                                uint8_t* __restrict__ ws) {
  const uint4* Wp   = (const uint4*)(ws + WIH_OFF);
  const float* bsum = (const float*)(ws + BSUM_OFF);
  _Float16*    xg   = (_Float16*)(ws + XG0_OFF);

  const int s = blockIdx.x >> 4;                       // col segment (64 cols), 16 segs
  const int m = ((blockIdx.x & 15) << 8) + threadIdx.x; // row 0..4095

  __shared__ uint4 wlds[1024];                         // 64 rows x 16 uint4
  __shared__ float bsl[64];
  #pragma unroll
  for (int i = 0; i < 4; ++i)
    wlds[i * 256 + threadIdx.x] = Wp[(size_t)(s << 6) * 16 + i * 256 + threadIdx.x];
  if (threadIdx.x < 64) bsl[threadIdx.x] = bsum[(s << 6) + threadIdx.x];
  __syncthreads();

  const float4* xr = (const float4*)(x + (size_t)m * IND);   // t0 = 0
  h2 xv[64];
  #pragma unroll
  for (int i = 0; i < 32; ++i) {
    float4 v = xr[i];
    xv[2*i  ].x = (_Float16)v.x; xv[2*i  ].y = (_Float16)v.y;
    xv[2*i+1].x = (_Float16)v.z; xv[2*i+1].y = (_Float16)v.w;
  }
  _Float16* xgrow = xg + (size_t)m * GG + (s << 6);
  for (int g = 0; g < 8; ++g) {
    float acc[8];
    #pragma unroll
    for (int j = 0; j < 8; ++j) {
      const uint4* wr = &wlds[(g * 8 + j) * 16];
      float a = bsl[g * 8 + j];
      #pragma unroll
      for (int q = 0; q < 16; ++q) {
        U16 w; w.u = wr[q];
        a = fdot2f(w.h[0], xv[4*q+0], a);
        a = fdot2f(w.h[1], xv[4*q+1], a);
        a = fdot2f(w.h[2], xv[4*q+2], a);
        a = fdot2f(w.h[3], xv[4*q+3], a);
      }
      acc[j] = a;
    }
    U16 o;
    #pragma unroll
    for (int p = 0; p < 4; ++p) { o.h[p].x = (_Float16)acc[2*p]; o.h[p].y = (_Float16)acc[2*p+1]; }
    *(uint4*)(xgrow + g * 8) = o.u;
  }
}

// ---------------- Fused per-chunk kernel: 3 wg roles ----------------
// grid 224 x 512 threads:
//   wg 0..63    consumer : recurrence for chunk ch (1 wg per batch element)
//   wg 64..191  producer : xg GEMM for chunk ch+1 (ping-pong buffer)
//   wg 192..223 y        : output projection of chunk ch-1 from hst ping-pong
//
// ROUND-8 (r0/r1/r4/r5/r6/r7 evidence): r7's cross-CU pair sync is fatally
// slow (~20us/step) -> single-CU-per-batch is mandatory. r5 proved there is
// BANDWIDTH SLACK (stream venue L2->scratch+HBM changed FETCH +8MB at zero
// time cost) -> the 4416 cy/step is latency/issue-bound on ~96 per-thread
// spilled-reload VMEM ops feeding dependent fdot2 chains at only 2
// waves/SIMD. Eliminate (not relocate) them: amdgpu_num_vgpr(256) directly
// overrides the allocator's 2-wg/CU occupancy heuristic (cap was 128 @
// 8 waves / 64 @ 16 waves; dynamic LDS hides the fact that only 1 wg/CU
// fits). HW pool = 512 regs/SIMD (m69), so 2 waves x 256 is exact.
// 192 weight h2 + ~40 working = ~232 <= 256 -> truly resident, pins keep
// them so. xg loaded at loop top (latency hides under dot phase).
__global__ void __launch_bounds__(512)
__attribute__((amdgpu_waves_per_eu(2, 2), amdgpu_num_vgpr(256)))
k2_fused(const float* __restrict__ x,
         uint8_t* __restrict__ ws,
         const float* __restrict__ b_out,
         float* __restrict__ out, int ch) {
  extern __shared__ __align__(16) uint8_t smem[];
  const int bi  = blockIdx.x;
  const int tid = threadIdx.x;

  if (bi < 64) {
    // ================= consumer =================
    if (ch >= NCH) return;
    const int b    = bi;
    const int u    = tid >> 1;                        // unit 0..255
    const int half = tid & 1;                         // k-half
    const int t0   = ch * TC;

    const uint4* WR = (const uint4*)(ws + WHH_OFF);   // [rr][q][u2]
    const uint4* WG = WR + 24576;                     // rr=3 (g rows)
    const unsigned short* xp = (const unsigned short*)(ws + ((ch & 1) ? XG1_OFF : XG0_OFF));
    _Float16* hst    = (_Float16*)(ws + ((ch & 1) ? HST1_OFF : HST0_OFF));
    _Float16* hstate = (_Float16*)(ws + HSTATE_OFF);
    float*    cstate = (float*)(ws + CSTATE_OFF);

    uint4*    gws   = (uint4*)smem;                   // [16][512] uint4 = 128 KB
    _Float16* h_lds = (_Float16*)(smem + 131072);     // [2][256] ping-pong, 1 KB

    // one-time: i/f/o half-rows into registers (192 h2); per-lane linear (u2==tid)
    h2 wi[64], wf[64], wo[64];
    #pragma unroll
    for (int q = 0; q < 16; ++q) {
      U16 a;
      a.u = WR[q * 512 + tid];
      wi[4*q+0]=a.h[0]; wi[4*q+1]=a.h[1]; wi[4*q+2]=a.h[2]; wi[4*q+3]=a.h[3];
      a.u = WR[8192 + q * 512 + tid];
      wf[4*q+0]=a.h[0]; wf[4*q+1]=a.h[1]; wf[4*q+2]=a.h[2]; wf[4*q+3]=a.h[3];
      a.u = WR[16384 + q * 512 + tid];
      wo[4*q+0]=a.h[0]; wo[4*q+1]=a.h[1]; wo[4*q+2]=a.h[2]; wo[4*q+3]=a.h[3];
    }
    // PIN: with a 256-reg budget these now stay truly resident; the pin
    // prevents the round-0/1 failure mode (loads sunk into the loop).
    #pragma unroll
    for (int k = 0; k < 64; ++k) {
      asm volatile("" : "+v"(wi[k]));
      asm volatile("" : "+v"(wf[k]));
      asm volatile("" : "+v"(wo[k]));
    }
    // one-time: stage all g rows into LDS (linear copy)
    #pragma unroll
    for (int j = 0; j < 16; ++j) gws[j * 512 + tid] = WG[j * 512 + tid];

    if (tid < 32) {                                   // h_{-1} -> buf0
      uint4 z = make_uint4(0u, 0u, 0u, 0u);
      ((uint4*)h_lds)[tid] = (t0 == 0) ? z : ((const uint4*)(hstate + (size_t)b * HH))[tid];
    }
    float c = 0.f;
    if (t0 != 0) c = cstate[(size_t)b * HH + u];      // both lanes of pair load same c

    const size_t xrow = (size_t)b * GG;
    __syncthreads();

    for (int tt = 0; tt < TC; ++tt) {
      // this step's xg at the TOP: ~900cy latency hides under the dot phase
      const size_t nx = xrow + (size_t)tt * (BB * GG);
      HU xi, xf, xgv, xo;
      xi.u  = xp[nx + u];
      xf.u  = xp[nx + 256 + u];
      xgv.u = xp[nx + 512 + u];
      xo.u  = xp[nx + 768 + u];

      float ai = 0.f, af = 0.f, ag = 0.f, ao = 0.f;
      // read h from buf[tt&1]; lane's k-half only (2 addresses per wave = free)
      const uint4* hv = ((const uint4*)h_lds) + (tt & 1) * 32 + half * 16;
      #pragma unroll
      for (int q = 0; q < 16; ++q) {
        U16 hh;  hh.u  = hv[q];
        U16 wg_; wg_.u = gws[q * 512 + tid];
        #pragma unroll
        for (int j = 0; j < 4; ++j) {
          ai = fdot2f(wi[4*q+j], hh.h[j], ai);
          af = fdot2f(wf[4*q+j], hh.h[j], af);
          ag = fdot2f(wg_.h[j],  hh.h[j], ag);
          ao = fdot2f(wo[4*q+j], hh.h[j], ao);
        }
      }
      // lane-pair partial exchange (k-half <-> k-half), commutative adds ->
      // both lanes get bitwise-identical sums
      ai += __shfl_xor(ai, 1);
      af += __shfl_xor(af, 1);
      ag += __shfl_xor(ag, 1);
      ao += __shfl_xor(ao, 1);
      float gi = sigm(ai + (float)xi.h);
      float gf = sigm(af + (float)xf.h);
      float gg = tanh_fast(ag + (float)xgv.h);
      float go = sigm(ao + (float)xo.h);
      c = gf * c + gi * gg;
      float hn = go * tanh_fast(c);
      if (half == 0) {                                // even lanes own the stores
        h_lds[((tt + 1) & 1) * HH + u] = (_Float16)hn;
        hst[((size_t)tt * BB + b) * HH + u] = (_Float16)hn;
        if (t0 + tt == TT - 1) {
          const size_t tail = (size_t)TT * BB * OUTD;
          out[tail + (size_t)b * HH + u] = hn;                       // h_T
          out[tail + (size_t)BB * HH + (size_t)b * HH + u] = c;      // c_T
        }
      }
      __syncthreads();                                // new h visible; old buf free
    }

    // persist state (TC even -> final h is in buf0)
    if (tid < 32) ((uint4*)(hstate + (size_t)b * HH))[tid] = ((const uint4*)h_lds)[tid];
    if (half == 0) cstate[(size_t)b * HH + u] = c;

  } else if (bi < 192) {
    // ================= producer: xg for chunk ch+1 =================
    if (ch + 1 >= NCH) return;
    const int p    = bi - 64;
    const int seg  = p >> 3;                          // 0..15 (64-col segment)
    const int rowg = p & 7;
    const int m    = rowg * 512 + tid;                // 0..4095
    const int t0n  = (ch + 1) * TC;

    const uint4* Wp   = (const uint4*)(ws + WIH_OFF);
    const float* bsum = (const float*)(ws + BSUM_OFF);
    _Float16*    xgn  = (_Float16*)(ws + (((ch + 1) & 1) ? XG1_OFF : XG0_OFF));

    uint4* wlds = (uint4*)smem;                       // 1024 uint4 = 16 KB
    float* bsl  = (float*)(smem + 16384);
    wlds[tid]       = Wp[(size_t)(seg << 6) * 16 + tid];
    wlds[tid + 512] = Wp[(size_t)(seg << 6) * 16 + 512 + tid];
    if (tid < 64) bsl[tid] = bsum[(seg << 6) + tid];
    __syncthreads();

    const float4* xr = (const float4*)(x + ((size_t)t0n * BB + m) * IND);
    h2 xv[64];
    #pragma unroll
    for (int i = 0; i < 32; ++i) {
      float4 v = xr[i];
      xv[2*i  ].x = (_Float16)v.x; xv[2*i  ].y = (_Float16)v.y;
      xv[2*i+1].x = (_Float16)v.z; xv[2*i+1].y = (_Float16)v.w;
    }
    _Float16* xgrow = xgn + (size_t)m * GG + (seg << 6);
    for (int g = 0; g < 8; ++g) {
      float acc[8];
      #pragma unroll
      for (int j = 0; j < 8; ++j) {
        const uint4* wr = &wlds[(g * 8 + j) * 16];
        float a = bsl[g * 8 + j];
        #pragma unroll
        for (int q = 0; q < 16; ++q) {
          U16 w; w.u = wr[q];
          a = fdot2f(w.h[0], xv[4*q+0], a);
          a = fdot2f(w.h[1], xv[4*q+1], a);
          a = fdot2f(w.h[2], xv[4*q+2], a);
          a = fdot2f(w.h[3], xv[4*q+3], a);
        }
        acc[j] = a;
      }
      U16 o;
      #pragma unroll
      for (int pk = 0; pk < 4; ++pk) { o.h[pk].x = (_Float16)acc[2*pk]; o.h[pk].y = (_Float16)acc[2*pk+1]; }
      *(uint4*)(xgrow + g * 8) = o.u;
    }

  } else {
    // ================= y: output projection for chunk ch-1 =================
    if (ch < 1) return;
    const int yb   = bi - 192;                        // 0..31
    const int seg  = yb & 15;                         // 8-col segment
    const int rowg = yb >> 4;                         // 0..1
    const int t0p  = (ch - 1) * TC;

    const _Float16* hstp = (const _Float16*)(ws + (((ch - 1) & 1) ? HST1_OFF : HST0_OFF));
    const uint4* WO = (const uint4*)(ws + WOUT_OFF);  // [128][32] uint4

    uint4* wlds = (uint4*)smem;                       // 256 uint4 = 4 KB
    float* bsl  = (float*)(smem + 4096);
    if (tid < 256) wlds[tid] = WO[(size_t)(seg * 8) * 32 + tid];
    if (tid < 8)   bsl[tid]  = b_out[seg * 8 + tid];
    __syncthreads();

    #pragma unroll
    for (int rr = 0; rr < 4; ++rr) {                  // 4 rows per thread
      const int r = rowg * 2048 + rr * 512 + tid;     // 0..4095
      const uint4* hr = (const uint4*)(hstp + (size_t)r * HH);
      float acc[8];
      #pragma unroll
      for (int j = 0; j < 8; ++j) acc[j] = bsl[j];
      #pragma unroll 4
      for (int q = 0; q < 32; ++q) {
        U16 hh; hh.u = hr[q];
        #pragma unroll
        for (int j = 0; j < 8; ++j) {
          U16 w; w.u = wlds[j * 32 + q];
          acc[j] = fdot2f(w.h[0], hh.h[0], acc[j]);
          acc[j] = fdot2f(w.h[1], hh.h[1], acc[j]);
          acc[j] = fdot2f(w.h[2], hh.h[2], acc[j]);
          acc[j] = fdot2f(w.h[3], hh.h[3], acc[j]);
        }
      }
      float* orow = out + ((size_t)t0p * BB + r) * OUTD + seg * 8;
      *(float4*)(orow)     = make_float4(acc[0], acc[1], acc[2], acc[3]);
      *(float4*)(orow + 4) = make_float4(acc[4], acc[5], acc[6], acc[7]);
    }
  }
}

extern "C" void kernel_launch(void* const* d_in, const int* in_sizes, int n_in,
                              void* d_out, int out_size, void* d_ws, size_t ws_size,
                              hipStream_t stream) {
  const float* input = (const float*)d_in[0];
  const float* W_ih  = (const float*)d_in[1];
  const float* W_hh  = (const float*)d_in[2];
  const float* b_ih  = (const float*)d_in[3];
  const float* b_hh  = (const float*)d_in[4];
  const float* W_out = (const float*)d_in[5];
  const float* b_out = (const float*)d_in[6];
  float*   out = (float*)d_out;
  uint8_t* ws  = (uint8_t*)d_ws;

  if (ws_size < WS_NEEDED) return;   // fail validation cleanly instead of faulting

  // allow 129 KB dynamic LDS (gfx950: 160 KB/CU); host-side + idempotent ->
  // safe under graph capture (proven in prior rounds).
  hipFuncSetAttribute((const void*)k2_fused,
                      hipFuncAttributeMaxDynamicSharedMemorySize, SMEM_SZ);

  hipLaunchKernelGGL(k0_pack,  dim3(324), dim3(256), 0, stream,
                     W_hh, W_ih, W_out, b_ih, b_hh, ws);
  hipLaunchKernelGGL(k1_xgemm, dim3(256), dim3(256), 0, stream, input, ws); // chunk 0 xg
  for (int ch = 0; ch <= NCH; ++ch) {   // ch==NCH: only y-role (last chunk's output)
    hipLaunchKernelGGL(k2_fused, dim3(224), dim3(512), SMEM_SZ, stream,
                       input, ws, b_out, out, ch);
  }
}